// Round 5
// baseline (255.380 us; speedup 1.0000x reference)
//
#include <hip/hip_runtime.h>

// Problem constants (reference: B=32, N=1024, D=384, max_len=4096)
#define BB 32
#define NN 1024
#define DD 384
#define ML 4096
#define D4 (DD / 4)            // 96 float4 per row
#define RPB 32                 // output rows per copy block
#define CT 384                 // copy threads/block
#define CITER (RPB * D4 / CT)  // 8 float4 per thread
#define NCB (BB * ML / RPB)    // 4096 copy blocks

typedef float floatx4 __attribute__((ext_vector_type(4)));

// Kernel 1: per-batch scan of durations + scatter-inverse of searchsorted.
// Produces idx[b][t] (x-row index, -1 if t >= total) and mask[b][t].
__global__ __launch_bounds__(NN) void lr_scan_scatter_kernel(
    const int* __restrict__ dur, int* __restrict__ idxb,
    float* __restrict__ mask) {
    __shared__ int s[NN];
    __shared__ int idx_lds[ML];
    const int b = blockIdx.x;
    const int i = threadIdx.x;

    s[i] = dur[b * NN + i];
    #pragma unroll
    for (int k = 0; k < ML / NN; ++k) idx_lds[i + k * NN] = -1;
    __syncthreads();

    // Hillis-Steele inclusive scan over 1024 elements
    #pragma unroll
    for (int off = 1; off < NN; off <<= 1) {
        int v = (i >= off) ? s[i - off] : 0;
        __syncthreads();
        s[i] += v;
        __syncthreads();
    }

    // x-row i owns t in [cum[i-1], cum[i]); clamp to ML (totals can exceed it)
    const int end_raw = s[i];
    const int start   = (i == 0) ? 0 : s[i - 1];
    const int end     = (end_raw < ML) ? end_raw : ML;
    for (int t = start; t < end; ++t) idx_lds[t] = i;
    __syncthreads();

    #pragma unroll
    for (int k = 0; k < ML / NN; ++k) {
        const int t = i + k * NN;
        const int v = idx_lds[t];
        idxb[b * ML + t] = v;
        mask[b * ML + t] = (v < 0) ? 1.0f : 0.0f;
    }
}

// Kernel 2: streaming gather-copy. 32 rows/block, idx staged once in LDS,
// plain (L2-buffered) stores, default block order, 8 independent
// load->store pairs per thread.
__global__ __launch_bounds__(CT) void lr_copy_kernel(
    const floatx4* __restrict__ x, const int* __restrict__ idxb,
    floatx4* __restrict__ out) {
    __shared__ int sidx[RPB];
    const int row0 = blockIdx.x * RPB;
    const int tid = threadIdx.x;

    if (tid < RPB) sidx[tid] = idxb[row0 + tid];
    __syncthreads();

    const int r0 = tid / D4;        // 0..3, computed once
    const int d4 = tid - r0 * D4;   // constant across iterations
    const int b  = row0 >> 12;      // batch is uniform per block (ML%RPB==0)
    const floatx4* __restrict__ xb = x + ((size_t)b << 10) * D4;

    #pragma unroll
    for (int k = 0; k < CITER; ++k) {
        const int r   = r0 + k * (CT / D4);   // +4 per iteration
        const int row = row0 + r;
        const int idx = sidx[r];
        floatx4 v = {0.0f, 0.0f, 0.0f, 0.0f};
        if (idx >= 0) v = xb[idx * D4 + d4];
        out[(size_t)row * D4 + d4] = v;
    }
}

extern "C" void kernel_launch(void* const* d_in, const int* in_sizes, int n_in,
                              void* d_out, int out_size, void* d_ws, size_t ws_size,
                              hipStream_t stream) {
    const float* x = (const float*)d_in[0];
    const int* dur = (const int*)d_in[1];
    // d_in[2] is max_len scalar; fixed at 4096 for this problem instance.

    int* idxb   = (int*)d_ws;                      // B*ML ints = 512 KB scratch
    float* out  = (float*)d_out;                   // (B, ML, D) fp32
    float* mask = out + (size_t)BB * ML * DD;      // (B, ML) as fp32 0/1

    lr_scan_scatter_kernel<<<BB, NN, 0, stream>>>(dur, idxb, mask);
    lr_copy_kernel<<<NCB, CT, 0, stream>>>(
        (const floatx4*)x, idxb, (floatx4*)out);
}